// Round 1
// baseline (632.066 us; speedup 1.0000x reference)
//
#include <hip/hip_runtime.h>

// ---------------------------------------------------------------------------
// Attention (B=8, S=2048, H=1024, fp32 in/out), all-f16 MFMA pipeline.
// q/k/v = relu(x@W^T + b); e = q@k^T - EPS*(1-mask); a = softmax(e); out = a@v + x
// Pipeline: cvt(x,W)->f16 ; GEMM_BT proj (q,k normal; v transposed) ;
//           per 2-batch round: scores GEMM -> softmax(f32->f16 P) -> PV GEMM + resid.
// All GEMMs are C = A @ B^T with A[M][K], Bt[N][K], both K-contiguous.
// ---------------------------------------------------------------------------

typedef __attribute__((ext_vector_type(8))) _Float16 f16x8;
typedef __attribute__((ext_vector_type(4))) _Float16 f16x4;
typedef __attribute__((ext_vector_type(4))) float    f32x4;

constexpr int  B_ = 8, S_ = 2048, H_ = 1024;
constexpr long SH = (long)S_ * H_;   // 2097152 elements per batch of q/k/v/x
constexpr long SS = (long)S_ * S_;   // 4194304 elements per batch of scores/P

#define DEVINL __device__ __forceinline__

#define EPI_PROJ   0  // f16 out[row][ldc] = relu(acc + bias[col])
#define EPI_PROJT  1  // f16 vt[(b*1024+col)*2048 + s] = relu(acc + bias[col])
#define EPI_SCORES 2  // f32 out[row][ldc] = acc              (per-z batch)
#define EPI_PV     3  // f32 out[row][ldc] = acc + resid[idx] (per-z batch)

// ---- async global->LDS, 16B per lane; LDS dest is wave-uniform base ----
DEVINL void stage_as(void* dst, const void* src) {
  __builtin_amdgcn_global_load_lds(
      (const __attribute__((address_space(1))) unsigned int*)src,
      (__attribute__((address_space(3))) unsigned int*)dst, 16, 0, 0);
}

// Stage a [ROWS][32] f16 tile (rows K-contiguous in global, row stride ldk).
// LDS layout is linear [row][32] but the 16B slot index is XOR-swizzled:
// LDS slot (row, s) holds global k-group (s ^ ((row>>1)&3)).  This is applied
// on the GLOBAL source side (global_load_lds writes linearly: lane i -> +16B*i).
template<int ROWS>
DEVINL void stage_tile(_Float16* lds, const _Float16* g, int ldk, int tid) {
#pragma unroll
  for (int h = 0; h < ROWS / 64; ++h) {
    int t   = tid + h * 256;            // virtual thread 0..(ROWS*4-1)
    int row = t >> 2;                   // 4 x 16B slots per 64B row
    int gs  = (t & 3) ^ ((row >> 1) & 3);
    stage_as(lds + h * 2048 + ((tid >> 6) << 9),  // wave-uniform base (elems)
             g + (long)row * ldk + gs * 8);
  }
}

// Read one 16x32 MFMA fragment: lane holds 8 contiguous k at row (lane&15),
// k-group (lane>>4), with the same XOR swizzle.  2-way bank conflict only.
DEVINL f16x8 frag(const _Float16* lds, int row, int lane) {
  int r   = row + (lane & 15);
  int off = r * 32 + ((((lane >> 4) ^ ((r >> 1) & 3))) << 3);
  return *(const f16x8*)(lds + off);
}

template<int EPI, int BM, int BN>
__global__ __launch_bounds__(256, 2)
void gemm_bt(const _Float16* __restrict__ A, const _Float16* __restrict__ Bt,
             int K, long aZ, long bZ, long cZ,
             const float* __restrict__ bias, const float* __restrict__ resid,
             void* __restrict__ outp, int ldc)
{
  constexpr int WN  = (BN == 128) ? 2 : 1;   // wave grid
  constexpr int WM  = 4 / WN;
  constexpr int WTM = BM / WM;               // per-wave tile rows
  constexpr int WTN = BN / WN;               // per-wave tile cols
  constexpr int MI  = WTM / 16;
  constexpr int NI  = WTN / 16;

  __shared__ alignas(16) _Float16 lA[BM * 32];
  __shared__ alignas(16) _Float16 lB[BN * 32];

  const int tid  = threadIdx.x;
  const int wid  = tid >> 6;
  const int lane = tid & 63;
  const int wm   = wid / WN, wn = wid % WN;
  const int z    = blockIdx.z;

  const _Float16* a0 = A  + (long)z * aZ + (long)blockIdx.x * BM * K;
  const _Float16* b0 = Bt + (long)z * bZ + (long)blockIdx.y * BN * K;

  f32x4 acc[MI][NI];
#pragma unroll
  for (int mi = 0; mi < MI; ++mi)
#pragma unroll
    for (int ni = 0; ni < NI; ++ni)
      acc[mi][ni] = (f32x4){0.f, 0.f, 0.f, 0.f};

  for (int k0 = 0; k0 < K; k0 += 32) {
    stage_tile<BM>(lA, a0 + k0, K, tid);
    stage_tile<BN>(lB, b0 + k0, K, tid);
    __syncthreads();   // drains vmcnt (global_load_lds) per compiler semantics
    f16x8 af[MI], bf[NI];
#pragma unroll
    for (int mi = 0; mi < MI; ++mi) af[mi] = frag(lA, wm * WTM + mi * 16, lane);
#pragma unroll
    for (int ni = 0; ni < NI; ++ni) bf[ni] = frag(lB, wn * WTN + ni * 16, lane);
#pragma unroll
    for (int mi = 0; mi < MI; ++mi)
#pragma unroll
      for (int ni = 0; ni < NI; ++ni)
        acc[mi][ni] = __builtin_amdgcn_mfma_f32_16x16x32_f16(af[mi], bf[ni], acc[mi][ni], 0, 0, 0);
    __syncthreads();
  }

  // Epilogue. C/D layout: col = lane&15, row = 4*(lane>>4) + r  [verified m89/m91]
  const int rb = blockIdx.x * BM + wm * WTM + ((lane >> 4) << 2);
  const int cb = blockIdx.y * BN + wn * WTN + (lane & 15);
#pragma unroll
  for (int mi = 0; mi < MI; ++mi) {
#pragma unroll
    for (int ni = 0; ni < NI; ++ni) {
      const int row0 = rb + mi * 16;
      const int col  = cb + ni * 16;
      if constexpr (EPI == EPI_PROJ) {
        _Float16* o = (_Float16*)outp;
        const float bv = bias[col];
#pragma unroll
        for (int r = 0; r < 4; ++r)
          o[(long)(row0 + r) * ldc + col] = (_Float16)fmaxf(acc[mi][ni][r] + bv, 0.f);
      } else if constexpr (EPI == EPI_PROJT) {
        _Float16* o = (_Float16*)outp;
        const float bv = bias[col];
        f16x4 pk;
#pragma unroll
        for (int r = 0; r < 4; ++r)
          pk[r] = (_Float16)fmaxf(acc[mi][ni][r] + bv, 0.f);
        const long b = row0 >> 11;          // batch (S=2048 rows per batch)
        const long s = row0 & 2047;         // multiple of 4 -> aligned f16x4
        *(f16x4*)(o + ((b << 10) + col) * 2048 + s) = pk;
      } else if constexpr (EPI == EPI_SCORES) {
        float* o = (float*)outp + (long)z * cZ;
#pragma unroll
        for (int r = 0; r < 4; ++r)
          o[(long)(row0 + r) * ldc + col] = acc[mi][ni][r];
      } else {  // EPI_PV
        float* o = (float*)outp + (long)z * cZ;
        const float* rs = resid + (long)z * cZ;
#pragma unroll
        for (int r = 0; r < 4; ++r) {
          const long idx = (long)(row0 + r) * ldc + col;
          o[idx] = acc[mi][ni][r] + rs[idx];
        }
      }
    }
  }
}

// ---- row softmax: one wave per row (2048 f32 -> 2048 f16), additive mask ----
__global__ __launch_bounds__(256)
void softmax_k(const float* __restrict__ Sc, const float* __restrict__ mask,
               _Float16* __restrict__ P)
{
  const int z    = blockIdx.y;
  const float*    s  = Sc + (long)z * SS;
  const float*    mk = mask + (long)z * S_;
  _Float16*       p  = P + (long)z * SS;
  const int row  = blockIdx.x * 4 + (threadIdx.x >> 6);
  const int lane = threadIdx.x & 63;

  const float4* sr = (const float4*)(s + (long)row * S_);
  const float4* mr = (const float4*)mk;
  float4 v[8];
  float  mx = -3.0e38f;
#pragma unroll
  for (int c = 0; c < 8; ++c) {
    float4 sv = sr[c * 64 + lane];
    float4 mv = mr[c * 64 + lane];
    sv.x -= 1e10f * (1.f - mv.x);
    sv.y -= 1e10f * (1.f - mv.y);
    sv.z -= 1e10f * (1.f - mv.z);
    sv.w -= 1e10f * (1.f - mv.w);
    v[c] = sv;
    mx = fmaxf(mx, fmaxf(fmaxf(sv.x, sv.y), fmaxf(sv.z, sv.w)));
  }
#pragma unroll
  for (int d = 32; d; d >>= 1) mx = fmaxf(mx, __shfl_xor(mx, d));
  float sum = 0.f;
#pragma unroll
  for (int c = 0; c < 8; ++c) {
    v[c].x = __expf(v[c].x - mx);
    v[c].y = __expf(v[c].y - mx);
    v[c].z = __expf(v[c].z - mx);
    v[c].w = __expf(v[c].w - mx);
    sum += (v[c].x + v[c].y) + (v[c].z + v[c].w);
  }
#pragma unroll
  for (int d = 32; d; d >>= 1) sum += __shfl_xor(sum, d);
  const float inv = 1.f / sum;
  f16x4* pr = (f16x4*)(p + (long)row * S_);
#pragma unroll
  for (int c = 0; c < 8; ++c) {
    f16x4 o = {(_Float16)(v[c].x * inv), (_Float16)(v[c].y * inv),
               (_Float16)(v[c].z * inv), (_Float16)(v[c].w * inv)};
    pr[c * 64 + lane] = o;
  }
}

// ---- fp32 -> f16 conversion, float4 per thread ----
__global__ __launch_bounds__(256)
void cvt_f16(const float* __restrict__ x, _Float16* __restrict__ y, int n4)
{
  const int i = blockIdx.x * 256 + threadIdx.x;
  if (i >= n4) return;
  const float4 v = ((const float4*)x)[i];
  f16x4 o = {(_Float16)v.x, (_Float16)v.y, (_Float16)v.z, (_Float16)v.w};
  ((f16x4*)y)[i] = o;
}

extern "C" void kernel_launch(void* const* d_in, const int* in_sizes, int n_in,
                              void* d_out, int out_size, void* d_ws, size_t ws_size,
                              hipStream_t stream)
{
  const float* input = (const float*)d_in[0];  // [8,2048,1024]
  const float* mask  = (const float*)d_in[1];  // [8,1,2048]
  const float* Wq    = (const float*)d_in[2];
  const float* bq    = (const float*)d_in[3];
  const float* Wk    = (const float*)d_in[4];
  const float* bk    = (const float*)d_in[5];
  const float* Wv    = (const float*)d_in[6];
  const float* bv    = (const float*)d_in[7];
  float* out = (float*)d_out;

  // workspace carve (182 MB total)
  char* w = (char*)d_ws;
  _Float16* xh  = (_Float16*)w; w += (size_t)B_ * SH * 2;   // 32 MB
  _Float16* wqh = (_Float16*)w; w += (size_t)H_ * H_ * 2;   //  2 MB
  _Float16* wkh = (_Float16*)w; w += (size_t)H_ * H_ * 2;
  _Float16* wvh = (_Float16*)w; w += (size_t)H_ * H_ * 2;
  _Float16* q   = (_Float16*)w; w += (size_t)B_ * SH * 2;   // 32 MB
  _Float16* k   = (_Float16*)w; w += (size_t)B_ * SH * 2;   // 32 MB
  _Float16* vt  = (_Float16*)w; w += (size_t)B_ * SH * 2;   // 32 MB  [b][d][s]
  float*    sc  = (float*)w;    w += (size_t)2 * SS * 4;    // 32 MB  (2 batches)
  _Float16* pb  = (_Float16*)w; w += (size_t)2 * SS * 2;    // 16 MB  (2 batches)

  // 1) fp32 -> f16 conversions
  cvt_f16<<<16384, 256, 0, stream>>>(input, xh, (int)(B_ * SH / 4));
  cvt_f16<<<1024, 256, 0, stream>>>(Wq, wqh, H_ * H_ / 4);
  cvt_f16<<<1024, 256, 0, stream>>>(Wk, wkh, H_ * H_ / 4);
  cvt_f16<<<1024, 256, 0, stream>>>(Wv, wvh, H_ * H_ / 4);

  // 2) projections: [16384,1024] = x @ W^T (+bias, relu)
  gemm_bt<EPI_PROJ, 128, 128><<<dim3(128, 8, 1), 256, 0, stream>>>(
      xh, wqh, H_, 0, 0, 0, bq, nullptr, q, H_);
  gemm_bt<EPI_PROJ, 128, 128><<<dim3(128, 8, 1), 256, 0, stream>>>(
      xh, wkh, H_, 0, 0, 0, bk, nullptr, k, H_);
  gemm_bt<EPI_PROJT, 128, 128><<<dim3(128, 8, 1), 256, 0, stream>>>(
      xh, wvh, H_, 0, 0, 0, bv, nullptr, vt, H_);

  // 3) attention, 2 batches per round (z dim), scores/P scratch reused
  for (int r = 0; r < 4; ++r) {
    const long b0 = (long)r * 2;
    gemm_bt<EPI_SCORES, 128, 128><<<dim3(16, 16, 2), 256, 0, stream>>>(
        q + b0 * SH, k + b0 * SH, H_, SH, SH, SS, nullptr, nullptr, sc, S_);
    softmax_k<<<dim3(512, 2), 256, 0, stream>>>(sc, mask + b0 * S_, pb);
    gemm_bt<EPI_PV, 128, 64><<<dim3(16, 16, 2), 256, 0, stream>>>(
        pb, vt + b0 * SH, S_, SS, SH, SH, nullptr, input + b0 * SH,
        out + b0 * SH, H_);
  }
}

// Round 2
// 449.454 us; speedup vs baseline: 1.4063x; 1.4063x over previous
//
#include <hip/hip_runtime.h>

// ---------------------------------------------------------------------------
// Attention (B=8, S=2048, H=1024, fp32 in/out), all-f16 MFMA pipeline.
// Round 2: BK=64, fused QKV projection, z=4 attention rounds, in-place P.
// All GEMMs are C = A @ B^T with A[M][K] (row stride lda), Bt[N][K] (ldb).
// ---------------------------------------------------------------------------

typedef __attribute__((ext_vector_type(8))) _Float16 f16x8;
typedef __attribute__((ext_vector_type(4))) _Float16 f16x4;
typedef __attribute__((ext_vector_type(4))) float    f32x4;

constexpr int  B_ = 8, S_ = 2048, H_ = 1024;
constexpr long SH = (long)S_ * H_;   // per-batch q/k/v/x elements
constexpr long SS = (long)S_ * S_;   // per-batch score elements

#define DEVINL __device__ __forceinline__

#define EPI_QKV    0  // fused projection: q/k straight, v transposed, relu+bias
#define EPI_SCORES 2  // f32 out[row][ldc] = acc              (per-z batch)
#define EPI_PV     3  // f32 out[row][ldc] = acc + resid[idx] (per-z batch)

// ---- async global->LDS, 16B per lane; LDS dest is wave-uniform base ----
DEVINL void stage_as(void* dst, const void* src) {
  __builtin_amdgcn_global_load_lds(
      (const __attribute__((address_space(1))) unsigned int*)src,
      (__attribute__((address_space(3))) unsigned int*)dst, 16, 0, 0);
}

// Stage a [ROWS][64] f16 tile (rows K-contiguous in global, row stride ldk).
// LDS is linear [row][64]; 16B slot at LDS pos p holds global slot p^(row&7)
// (swizzle applied on the GLOBAL source: global_load_lds writes lane i -> +16B*i).
template<int ROWS>
DEVINL void stage_tile(_Float16* lds, const _Float16* g, int ldk, int tid) {
#pragma unroll
  for (int h = 0; h < ROWS / 32; ++h) {
    int t   = tid + h * 256;            // virtual thread, 8 x 16B slots per row
    int row = t >> 3;
    int gs  = (t & 7) ^ (row & 7);
    stage_as(lds + (h * 256 + (tid >> 6) * 64) * 8,   // wave-uniform base (elems)
             g + (long)row * ldk + gs * 8);
  }
}

// Read one 16x32 MFMA fragment for k-substep kk (0/1): lane holds 8 contiguous
// k at row (lane&15), logical slot kk*4+(lane>>4), stored XOR-swizzled.
DEVINL f16x8 frag(const _Float16* lds, int row, int kk, int lane) {
  int r = row + (lane & 15);
  int s = (kk * 4 + (lane >> 4)) ^ (r & 7);
  return *(const f16x8*)(lds + r * 64 + s * 8);
}

template<int EPI, int BM, int BN>
__global__ __launch_bounds__(256, 2)
void gemm_bt(const _Float16* __restrict__ A, const _Float16* __restrict__ Bt,
             int K, int lda, int ldb, long aZ, long bZ, long cZ,
             const float* __restrict__ bs0, const float* __restrict__ bs1,
             const float* __restrict__ bs2, const float* __restrict__ resid,
             void* __restrict__ o0, void* __restrict__ o1, void* __restrict__ o2,
             int ldc)
{
  constexpr int WN  = (BN == 128) ? 2 : 1;   // wave grid
  constexpr int WM  = 4 / WN;
  constexpr int WTM = BM / WM;               // per-wave tile rows
  constexpr int WTN = BN / WN;               // per-wave tile cols
  constexpr int MI  = WTM / 16;
  constexpr int NI  = WTN / 16;

  __shared__ alignas(16) _Float16 lA[BM * 64];
  __shared__ alignas(16) _Float16 lB[BN * 64];

  const int tid  = threadIdx.x;
  const int wid  = tid >> 6;
  const int lane = tid & 63;
  const int wm   = wid / WN, wn = wid % WN;
  const int z    = blockIdx.z;

  const _Float16* a0 = A  + (long)z * aZ + (long)blockIdx.x * BM * lda;
  const _Float16* b0 = Bt + (long)z * bZ + (long)blockIdx.y * BN * ldb;

  f32x4 acc[MI][NI];
#pragma unroll
  for (int mi = 0; mi < MI; ++mi)
#pragma unroll
    for (int ni = 0; ni < NI; ++ni)
      acc[mi][ni] = (f32x4){0.f, 0.f, 0.f, 0.f};

  for (int k0 = 0; k0 < K; k0 += 64) {
    stage_tile<BM>(lA, a0 + k0, lda, tid);
    stage_tile<BN>(lB, b0 + k0, ldb, tid);
    __syncthreads();   // drains vmcnt (global_load_lds) per compiler semantics
#pragma unroll
    for (int kk = 0; kk < 2; ++kk) {
      f16x8 af[MI], bf[NI];
#pragma unroll
      for (int mi = 0; mi < MI; ++mi) af[mi] = frag(lA, wm * WTM + mi * 16, kk, lane);
#pragma unroll
      for (int ni = 0; ni < NI; ++ni) bf[ni] = frag(lB, wn * WTN + ni * 16, kk, lane);
#pragma unroll
      for (int mi = 0; mi < MI; ++mi)
#pragma unroll
        for (int ni = 0; ni < NI; ++ni)
          acc[mi][ni] = __builtin_amdgcn_mfma_f32_16x16x32_f16(af[mi], bf[ni], acc[mi][ni], 0, 0, 0);
    }
    __syncthreads();
  }

  // Epilogue. C/D layout: col = lane&15, row = 4*(lane>>4) + r  [verified]
  const int rb = blockIdx.x * BM + wm * WTM + ((lane >> 4) << 2);
  const int cb = blockIdx.y * BN + wn * WTN + (lane & 15);
#pragma unroll
  for (int mi = 0; mi < MI; ++mi) {
#pragma unroll
    for (int ni = 0; ni < NI; ++ni) {
      const int row0 = rb + mi * 16;
      const int col  = cb + ni * 16;
      if constexpr (EPI == EPI_QKV) {
        // col in [0,3072): section 0->q, 1->k, 2->v(transposed)
        const int sect = col >> 10;            // block-uniform (BN=128 | 1024)
        const int c    = col & 1023;
        const float* bias = (sect == 0) ? bs0 : (sect == 1) ? bs1 : bs2;
        const float bv = bias[c];
        if (sect < 2) {
          _Float16* o = (_Float16*)(sect == 0 ? o0 : o1);
#pragma unroll
          for (int r = 0; r < 4; ++r)
            o[(long)(row0 + r) * 1024 + c] = (_Float16)fmaxf(acc[mi][ni][r] + bv, 0.f);
        } else {
          _Float16* o = (_Float16*)o2;          // vt[(b*1024+c)*2048 + s]
          f16x4 pk;
#pragma unroll
          for (int r = 0; r < 4; ++r)
            pk[r] = (_Float16)fmaxf(acc[mi][ni][r] + bv, 0.f);
          const long b = row0 >> 11;            // batch (S=2048 rows per batch)
          const long s = row0 & 2047;           // multiple of 4 -> aligned f16x4
          *(f16x4*)(o + ((b << 10) + c) * 2048 + s) = pk;
        }
      } else if constexpr (EPI == EPI_SCORES) {
        float* o = (float*)o0 + (long)z * cZ;
#pragma unroll
        for (int r = 0; r < 4; ++r)
          o[(long)(row0 + r) * ldc + col] = acc[mi][ni][r];
      } else {  // EPI_PV
        float* o = (float*)o0 + (long)z * cZ;
        const float* rs = resid + (long)z * cZ;
#pragma unroll
        for (int r = 0; r < 4; ++r) {
          const long idx = (long)(row0 + r) * ldc + col;
          o[idx] = acc[mi][ni][r] + rs[idx];
        }
      }
    }
  }
}

// ---- row softmax, IN PLACE: reads f32 row, writes f16 P into the row start.
// One wave per row. All reads feed both reductions, so every load completes
// before the first store issues (no in-row RAW hazard).
__global__ __launch_bounds__(256)
void softmax_k(float* __restrict__ Sc, const float* __restrict__ mask)
{
  const int z    = blockIdx.y;
  float*       s  = Sc + (long)z * SS;
  const float* mk = mask + (long)z * S_;
  const int row  = blockIdx.x * 4 + (threadIdx.x >> 6);
  const int lane = threadIdx.x & 63;

  const float4* sr = (const float4*)(s + (long)row * S_);
  const float4* mr = (const float4*)mk;
  float4 v[8];
  float  mx = -3.0e38f;
#pragma unroll
  for (int c = 0; c < 8; ++c) {
    float4 sv = sr[c * 64 + lane];
    float4 mv = mr[c * 64 + lane];
    sv.x -= 1e10f * (1.f - mv.x);
    sv.y -= 1e10f * (1.f - mv.y);
    sv.z -= 1e10f * (1.f - mv.z);
    sv.w -= 1e10f * (1.f - mv.w);
    v[c] = sv;
    mx = fmaxf(mx, fmaxf(fmaxf(sv.x, sv.y), fmaxf(sv.z, sv.w)));
  }
#pragma unroll
  for (int d = 32; d; d >>= 1) mx = fmaxf(mx, __shfl_xor(mx, d));
  float sum = 0.f;
#pragma unroll
  for (int c = 0; c < 8; ++c) {
    v[c].x = __expf(v[c].x - mx);
    v[c].y = __expf(v[c].y - mx);
    v[c].z = __expf(v[c].z - mx);
    v[c].w = __expf(v[c].w - mx);
    sum += (v[c].x + v[c].y) + (v[c].z + v[c].w);
  }
#pragma unroll
  for (int d = 32; d; d >>= 1) sum += __shfl_xor(sum, d);
  const float inv = 1.f / sum;
  f16x4* pr = (f16x4*)(s + (long)row * S_);   // in-place: f16 row over f32 row
#pragma unroll
  for (int c = 0; c < 8; ++c) {
    f16x4 o = {(_Float16)(v[c].x * inv), (_Float16)(v[c].y * inv),
               (_Float16)(v[c].z * inv), (_Float16)(v[c].w * inv)};
    pr[c * 64 + lane] = o;
  }
}

// ---- fp32 -> f16 conversion, float4 per thread ----
__global__ __launch_bounds__(256)
void cvt_f16(const float* __restrict__ x, _Float16* __restrict__ y, int n4)
{
  const int i = blockIdx.x * 256 + threadIdx.x;
  if (i >= n4) return;
  const float4 v = ((const float4*)x)[i];
  f16x4 o = {(_Float16)v.x, (_Float16)v.y, (_Float16)v.z, (_Float16)v.w};
  ((f16x4*)y)[i] = o;
}

// three weight matrices -> one contiguous [3072][1024] f16 matrix
__global__ __launch_bounds__(256)
void cvt_w3(const float* __restrict__ a, const float* __restrict__ b,
            const float* __restrict__ c, _Float16* __restrict__ y)
{
  const int i = blockIdx.x * 256 + threadIdx.x;       // n4 = 1024*1024/4
  const float* src = (blockIdx.y == 0) ? a : (blockIdx.y == 1) ? b : c;
  const float4 v = ((const float4*)src)[i];
  f16x4 o = {(_Float16)v.x, (_Float16)v.y, (_Float16)v.z, (_Float16)v.w};
  ((f16x4*)(y + (long)blockIdx.y * H_ * H_))[i] = o;
}

extern "C" void kernel_launch(void* const* d_in, const int* in_sizes, int n_in,
                              void* d_out, int out_size, void* d_ws, size_t ws_size,
                              hipStream_t stream)
{
  const float* input = (const float*)d_in[0];  // [8,2048,1024]
  const float* mask  = (const float*)d_in[1];  // [8,1,2048]
  const float* Wq    = (const float*)d_in[2];
  const float* bq    = (const float*)d_in[3];
  const float* Wk    = (const float*)d_in[4];
  const float* bk    = (const float*)d_in[5];
  const float* Wv    = (const float*)d_in[6];
  const float* bv    = (const float*)d_in[7];
  float* out = (float*)d_out;

  // workspace carve (peak 160 MB; xh/wAll dead before sc is written)
  char* w = (char*)d_ws;
  _Float16* q    = (_Float16*)(w);                     // 32 MB [0,32)
  _Float16* k    = (_Float16*)(w + (32l << 20));       // 32 MB [32,64)
  _Float16* vt   = (_Float16*)(w + (64l << 20));       // 32 MB [64,96)  [b][d][s]
  _Float16* xh   = (_Float16*)(w + (96l << 20));       // 32 MB [96,128) (dead after proj)
  _Float16* wAll = (_Float16*)(w + (128l << 20));      //  6 MB [128,134) (dead after proj)
  float*    sc   = (float*)   (w + (96l << 20));       // 64 MB [96,160) (4 batches f32)

  // 1) fp32 -> f16 conversions
  cvt_f16<<<16384, 256, 0, stream>>>(input, xh, (int)(B_ * SH / 4));
  cvt_w3<<<dim3(1024, 3), 256, 0, stream>>>(Wq, Wk, Wv, wAll);

  // 2) fused QKV projection: [16384,3072] = x @ [Wq;Wk;Wv]^T (+bias, relu)
  gemm_bt<EPI_QKV, 128, 128><<<dim3(128, 24, 1), 256, 0, stream>>>(
      xh, wAll, H_, H_, H_, 0, 0, 0, bq, bk, bv, nullptr, q, k, vt, 0);

  // 3) attention, 4 batches per round (z dim), scores/P scratch reused
  for (int r = 0; r < 2; ++r) {
    const long b0 = (long)r * 4;
    gemm_bt<EPI_SCORES, 128, 128><<<dim3(16, 16, 4), 256, 0, stream>>>(
        q + b0 * SH, k + b0 * SH, H_, H_, H_, SH, SH, SS,
        nullptr, nullptr, nullptr, nullptr, sc, nullptr, nullptr, S_);
    softmax_k<<<dim3(512, 4), 256, 0, stream>>>(sc, mask + b0 * S_);
    gemm_bt<EPI_PV, 128, 64><<<dim3(16, 16, 4), 256, 0, stream>>>(
        (const _Float16*)sc, vt + b0 * SH, S_, 2 * S_, S_, 2 * SS, SH, SH,
        nullptr, nullptr, nullptr, input + b0 * SH, out + b0 * SH, nullptr, nullptr, H_);
  }
}

// Round 3
// 442.441 us; speedup vs baseline: 1.4286x; 1.0158x over previous
//
#include <hip/hip_runtime.h>

// ---------------------------------------------------------------------------
// Attention (B=8, S=2048, H=1024, fp32 in/out), all-f16 MFMA pipeline.
// Round 3: deep-pipelined GEMM — BK=32, 4-slot LDS ring, prefetch distance 3,
// counted s_waitcnt vmcnt(N) (never 0 in main loop), raw s_barrier, setprio.
// All GEMMs are C = A @ B^T with A[M][K] (row stride lda), Bt[N][K] (ldb).
// ---------------------------------------------------------------------------

typedef __attribute__((ext_vector_type(8))) _Float16 f16x8;
typedef __attribute__((ext_vector_type(4))) _Float16 f16x4;
typedef __attribute__((ext_vector_type(4))) float    f32x4;

constexpr int  B_ = 8, S_ = 2048, H_ = 1024;
constexpr long SH = (long)S_ * H_;   // per-batch q/k/v/x elements
constexpr long SS = (long)S_ * S_;   // per-batch score elements

#define DEVINL __device__ __forceinline__
template<int N> struct ic { static constexpr int v = N; };

#define EPI_QKV    0  // fused projection: q/k straight, v transposed, relu+bias
#define EPI_SCORES 2  // f32 out[row][ldc] = acc              (per-z batch)
#define EPI_PV     3  // f32 out[row][ldc] = acc + resid[idx] (per-z batch)

// ---- async global->LDS, 16B per lane; LDS dest is wave-uniform base ----
DEVINL void stage_as(void* dst, const void* src) {
  __builtin_amdgcn_global_load_lds(
      (const __attribute__((address_space(1))) unsigned int*)src,
      (__attribute__((address_space(3))) unsigned int*)dst, 16, 0, 0);
}

// Stage a [ROWS][32] f16 tile with 512 threads. LDS linear [row][32]; the 16B
// slot at LDS pos s holds global k-group s^((row>>1)&3) (swizzle applied on the
// GLOBAL source; global_load_lds writes lane i -> +16B*i).  Verified 2-way
// (free) bank conflicts on the paired frag() read (R1 counters: 0 conflicts).
template<int ROWS>
DEVINL void stage_mat(_Float16* ldsb, const _Float16* g, int ldk, int tid) {
#pragma unroll
  for (int h = 0; h < ROWS / 128; ++h) {
    int t   = tid + h * 512;            // virtual thread, 4 x 16B slots per row
    int row = t >> 2;
    int gs  = (t & 3) ^ ((row >> 1) & 3);
    stage_as(ldsb + h * 4096 + ((tid >> 6) << 9),   // wave-uniform base (elems)
             g + (long)row * ldk + gs * 8);
  }
}

// Read one 16x32 MFMA fragment: lane holds 8 contiguous k at row (lane&15),
// k-group (lane>>4), stored XOR-swizzled.  2-way bank conflict only.
DEVINL f16x8 frag(const _Float16* lds, int row, int lane) {
  int r   = row + (lane & 15);
  int off = r * 32 + (((lane >> 4) ^ ((r >> 1) & 3)) << 3);
  return *(const f16x8*)(lds + off);
}

template<int EPI, int BM, int BN>
__global__ __launch_bounds__(512, 1)
void gemm_p(const _Float16* __restrict__ A, const _Float16* __restrict__ Bt,
            int K, int lda, int ldb, long aZ, long bZ, long cZ,
            const float* __restrict__ bs0, const float* __restrict__ bs1,
            const float* __restrict__ bs2, const float* __restrict__ resid,
            void* __restrict__ o0, void* __restrict__ o1, void* __restrict__ o2,
            int ldc)
{
  constexpr int WTM  = BM / 2;               // 8 waves as 2 (M) x 4 (N)
  constexpr int WTN  = BN / 4;
  constexpr int MI   = WTM / 16;
  constexpr int NI   = WTN / 16;
  constexpr int ASLOT = BM * 32;             // f16 elems per ring slot
  constexpr int SLOT  = (BM + BN) * 32;
  constexpr int LPT   = (BM + BN) / 128;     // global_load_lds per thread/slot

  __shared__ alignas(16) _Float16 lds[4 * SLOT];   // 4-slot ring

  const int tid  = threadIdx.x;
  const int wid  = tid >> 6;
  const int lane = tid & 63;
  const int wm   = wid >> 2, wn = wid & 3;
  const int z    = blockIdx.z;

  const _Float16* a0 = A  + (long)z * aZ + (long)blockIdx.x * BM * lda;
  const _Float16* b0 = Bt + (long)z * bZ + (long)blockIdx.y * BN * ldb;

  f32x4 acc[MI][NI];
#pragma unroll
  for (int mi = 0; mi < MI; ++mi)
#pragma unroll
    for (int ni = 0; ni < NI; ++ni)
      acc[mi][ni] = (f32x4){0.f, 0.f, 0.f, 0.f};

  const int NT = K >> 5;                     // K-tiles of 32

  auto stage = [&](int t) {                  // slot t -> ring[t&3]
    _Float16* s = lds + (size_t)(t & 3) * SLOT;
    stage_mat<BM>(s,         a0 + t * 32, lda, tid);
    stage_mat<BN>(s + ASLOT, b0 + t * 32, ldb, tid);
  };

  // Invariants: ring[(t)&3] is overwritten only by stage(t+4), issued after the
  // end-of-iter-t barrier (all reads of slot t done).  Before computing slot t,
  // vmcnt(<=3*LPT) drains t's loads (FIFO order), then s_barrier publishes them.
  auto iter = [&](auto vm, int kt, bool dostage) {
    if (dostage) stage(kt + 3);
    asm volatile("s_waitcnt vmcnt(%0)" :: "n"(decltype(vm)::v) : "memory");
    __builtin_amdgcn_s_barrier();
    asm volatile("" ::: "memory");
    const _Float16* sA = lds + (size_t)(kt & 3) * SLOT;
    const _Float16* sB = sA + ASLOT;
    f16x8 af[MI], bf[NI];
#pragma unroll
    for (int mi = 0; mi < MI; ++mi) af[mi] = frag(sA, wm * WTM + mi * 16, lane);
#pragma unroll
    for (int ni = 0; ni < NI; ++ni) bf[ni] = frag(sB, wn * WTN + ni * 16, lane);
    __builtin_amdgcn_s_setprio(1);
#pragma unroll
    for (int mi = 0; mi < MI; ++mi)
#pragma unroll
      for (int ni = 0; ni < NI; ++ni)
        acc[mi][ni] = __builtin_amdgcn_mfma_f32_16x16x32_f16(af[mi], bf[ni], acc[mi][ni], 0, 0, 0);
    __builtin_amdgcn_s_setprio(0);
    asm volatile("" ::: "memory");
    __builtin_amdgcn_s_barrier();            // frees ring[kt&3] for stage(kt+4)
  };

  stage(0); stage(1); stage(2);              // prologue: 3 slots in flight
  int kt = 0;
  for (; kt < NT - 3; ++kt) iter(ic<3 * LPT>{}, kt, true);
  iter(ic<2 * LPT>{}, kt, false); ++kt;      // tail: shrinking in-flight counts
  iter(ic<1 * LPT>{}, kt, false); ++kt;
  iter(ic<0>{},       kt, false);

  // Epilogue. C/D layout: col = lane&15, row = 4*(lane>>4) + r  [verified]
  const int rb = blockIdx.x * BM + wm * WTM + ((lane >> 4) << 2);
  const int cb = blockIdx.y * BN + wn * WTN + (lane & 15);
#pragma unroll
  for (int mi = 0; mi < MI; ++mi) {
#pragma unroll
    for (int ni = 0; ni < NI; ++ni) {
      const int row0 = rb + mi * 16;
      const int col  = cb + ni * 16;
      if constexpr (EPI == EPI_QKV) {
        // col in [0,3072): section 0->q, 1->k, 2->v(transposed)
        const int sect = col >> 10;
        const int c    = col & 1023;
        const float* bias = (sect == 0) ? bs0 : (sect == 1) ? bs1 : bs2;
        const float bv = bias[c];
        if (sect < 2) {
          _Float16* o = (_Float16*)(sect == 0 ? o0 : o1);
#pragma unroll
          for (int r = 0; r < 4; ++r)
            o[(long)(row0 + r) * 1024 + c] = (_Float16)fmaxf(acc[mi][ni][r] + bv, 0.f);
        } else {
          _Float16* o = (_Float16*)o2;        // vt[(b*1024+c)*2048 + s]
          f16x4 pk;
#pragma unroll
          for (int r = 0; r < 4; ++r)
            pk[r] = (_Float16)fmaxf(acc[mi][ni][r] + bv, 0.f);
          const long b = row0 >> 11;          // batch (S=2048 rows per batch)
          const long s = row0 & 2047;         // multiple of 4 -> aligned f16x4
          *(f16x4*)(o + ((b << 10) + c) * 2048 + s) = pk;
        }
      } else if constexpr (EPI == EPI_SCORES) {
        float* o = (float*)o0 + (long)z * cZ;
#pragma unroll
        for (int r = 0; r < 4; ++r)
          o[(long)(row0 + r) * ldc + col] = acc[mi][ni][r];
      } else {  // EPI_PV
        float* o = (float*)o0 + (long)z * cZ;
        const float* rs = resid + (long)z * cZ;
#pragma unroll
        for (int r = 0; r < 4; ++r) {
          const long idx = (long)(row0 + r) * ldc + col;
          o[idx] = acc[mi][ni][r] + rs[idx];
        }
      }
    }
  }
}

// ---- row softmax, IN PLACE: reads f32 row, writes f16 P into the row start.
__global__ __launch_bounds__(256)
void softmax_k(float* __restrict__ Sc, const float* __restrict__ mask)
{
  const int z    = blockIdx.y;
  float*       s  = Sc + (long)z * SS;
  const float* mk = mask + (long)z * S_;
  const int row  = blockIdx.x * 4 + (threadIdx.x >> 6);
  const int lane = threadIdx.x & 63;

  const float4* sr = (const float4*)(s + (long)row * S_);
  const float4* mr = (const float4*)mk;
  float4 v[8];
  float  mx = -3.0e38f;
#pragma unroll
  for (int c = 0; c < 8; ++c) {
    float4 sv = sr[c * 64 + lane];
    float4 mv = mr[c * 64 + lane];
    sv.x -= 1e10f * (1.f - mv.x);
    sv.y -= 1e10f * (1.f - mv.y);
    sv.z -= 1e10f * (1.f - mv.z);
    sv.w -= 1e10f * (1.f - mv.w);
    v[c] = sv;
    mx = fmaxf(mx, fmaxf(fmaxf(sv.x, sv.y), fmaxf(sv.z, sv.w)));
  }
#pragma unroll
  for (int d = 32; d; d >>= 1) mx = fmaxf(mx, __shfl_xor(mx, d));
  float sum = 0.f;
#pragma unroll
  for (int c = 0; c < 8; ++c) {
    v[c].x = __expf(v[c].x - mx);
    v[c].y = __expf(v[c].y - mx);
    v[c].z = __expf(v[c].z - mx);
    v[c].w = __expf(v[c].w - mx);
    sum += (v[c].x + v[c].y) + (v[c].z + v[c].w);
  }
#pragma unroll
  for (int d = 32; d; d >>= 1) sum += __shfl_xor(sum, d);
  const float inv = 1.f / sum;
  f16x4* pr = (f16x4*)(s + (long)row * S_);   // in-place: f16 row over f32 row
#pragma unroll
  for (int c = 0; c < 8; ++c) {
    f16x4 o = {(_Float16)(v[c].x * inv), (_Float16)(v[c].y * inv),
               (_Float16)(v[c].z * inv), (_Float16)(v[c].w * inv)};
    pr[c * 64 + lane] = o;
  }
}

// ---- fp32 -> f16 conversion, float4 per thread ----
__global__ __launch_bounds__(256)
void cvt_f16(const float* __restrict__ x, _Float16* __restrict__ y, int n4)
{
  const int i = blockIdx.x * 256 + threadIdx.x;
  if (i >= n4) return;
  const float4 v = ((const float4*)x)[i];
  f16x4 o = {(_Float16)v.x, (_Float16)v.y, (_Float16)v.z, (_Float16)v.w};
  ((f16x4*)y)[i] = o;
}

// three weight matrices -> one contiguous [3072][1024] f16 matrix
__global__ __launch_bounds__(256)
void cvt_w3(const float* __restrict__ a, const float* __restrict__ b,
            const float* __restrict__ c, _Float16* __restrict__ y)
{
  const int i = blockIdx.x * 256 + threadIdx.x;       // n4 = 1024*1024/4
  const float* src = (blockIdx.y == 0) ? a : (blockIdx.y == 1) ? b : c;
  const float4 v = ((const float4*)src)[i];
  f16x4 o = {(_Float16)v.x, (_Float16)v.y, (_Float16)v.z, (_Float16)v.w};
  ((f16x4*)(y + (long)blockIdx.y * H_ * H_))[i] = o;
}

extern "C" void kernel_launch(void* const* d_in, const int* in_sizes, int n_in,
                              void* d_out, int out_size, void* d_ws, size_t ws_size,
                              hipStream_t stream)
{
  const float* input = (const float*)d_in[0];  // [8,2048,1024]
  const float* mask  = (const float*)d_in[1];  // [8,1,2048]
  const float* Wq    = (const float*)d_in[2];
  const float* bq    = (const float*)d_in[3];
  const float* Wk    = (const float*)d_in[4];
  const float* bk    = (const float*)d_in[5];
  const float* Wv    = (const float*)d_in[6];
  const float* bv    = (const float*)d_in[7];
  float* out = (float*)d_out;

  // workspace carve (peak 160 MB; xh/wAll dead before sc is written)
  char* w = (char*)d_ws;
  _Float16* q    = (_Float16*)(w);                     // 32 MB [0,32)
  _Float16* k    = (_Float16*)(w + (32l << 20));       // 32 MB [32,64)
  _Float16* vt   = (_Float16*)(w + (64l << 20));       // 32 MB [64,96)  [b][d][s]
  _Float16* xh   = (_Float16*)(w + (96l << 20));       // 32 MB [96,128) (dead after proj)
  _Float16* wAll = (_Float16*)(w + (128l << 20));      //  6 MB [128,134) (dead after proj)
  float*    sc   = (float*)   (w + (96l << 20));       // 64 MB [96,160) (4 batches f32)

  // 1) fp32 -> f16 conversions
  cvt_f16<<<16384, 256, 0, stream>>>(input, xh, (int)(B_ * SH / 4));
  cvt_w3<<<dim3(1024, 3), 256, 0, stream>>>(Wq, Wk, Wv, wAll);

  // 2) fused QKV projection: [16384,3072] = x @ [Wq;Wk;Wv]^T (+bias, relu)
  gemm_p<EPI_QKV, 256, 256><<<dim3(64, 12, 1), 512, 0, stream>>>(
      xh, wAll, H_, H_, H_, 0, 0, 0, bq, bk, bv, nullptr, q, k, vt, 0);

  // 3) attention, 4 batches per round (z dim), scores/P scratch reused
  for (int r = 0; r < 2; ++r) {
    const long b0 = (long)r * 4;
    gemm_p<EPI_SCORES, 256, 256><<<dim3(8, 8, 4), 512, 0, stream>>>(
        q + b0 * SH, k + b0 * SH, H_, H_, H_, SH, SH, SS,
        nullptr, nullptr, nullptr, nullptr, sc, nullptr, nullptr, S_);
    softmax_k<<<dim3(512, 4), 256, 0, stream>>>(sc, mask + b0 * S_);
    gemm_p<EPI_PV, 256, 128><<<dim3(8, 8, 4), 512, 0, stream>>>(
        (const _Float16*)sc, vt + b0 * SH, S_, 2 * S_, S_, 2 * SS, SH, SH,
        nullptr, nullptr, nullptr, input + b0 * SH, out + b0 * SH, nullptr, nullptr, H_);
  }
}